// Round 18
// baseline (83.288 us; speedup 1.0000x reference)
//
#include <hip/hip_runtime.h>

// Event-to-image: B=16, N=500000 events (t,x,y,p) f32 -> (16,720,1280,3) f32.
// Last-event-wins per pixel: p==1 -> (0,255,255); p==0 -> (255,0,255);
// untouched -> (255,255,510). Order-independent via max over
// key = ((event_idx+1)<<1)|p (20 bits), pk = pos<<20 | key,
// pos = (y - 3*band)*1280 + x (<3840, 12 bits) -- 3-ROW BANDS (240/batch).
//
// R18 = R17 with ONE change: render's output stores are PLAIN float4
// (write-back through L2), not nontemporal. Evidence: render runs its
// 212MB at 4.1 TB/s while the harness fill kernel streams 691MB at 7 TB/s
// with plain stores; per-op and per-block costs are falsified (R15/R17),
// leaving the nt write path as the 2x write-BW suspect (never isolated:
// R6 bundled nt stores with two other changes).

#define WIDTH   1280
#define HEIGHT  720
#define BATCH   16
#define NEV     500000
#define THREADS 512                         // scatter block
#define EPT     16
#define EVPB    (THREADS * EPT)             // 8192 events per block
#define BPB     ((NEV + EVPB - 1) / EVPB)   // 62 blocks per batch
#define NBLK    (BATCH * BPB)               // 992
#define NBANDS  240                         // 3-row bands per batch
#define PH      (NBANDS + 1)                // 241 prefix rows
#define RTHREADS 256                        // render block
#define BPX     (3 * WIDTH)                 // 3840 pixels per band

typedef float f4 __attribute__((ext_vector_type(4)));

// ws layout: [0, PH*BATCH*BPB*4)=pref_g (956 KB, band-major);
//            [0x400000, +NBLK*EVPB*4)=bins (32.5 MB)

__global__ __launch_bounds__(THREADS, 8) void scatter_k(const float4* __restrict__ ev,
                                                        unsigned int* __restrict__ pref_g,
                                                        unsigned int* __restrict__ bins) {
    __shared__ unsigned int hist[NBANDS];
    __shared__ unsigned int offs[NBANDS];
    __shared__ unsigned int stage[EVPB];     // 32 KB (total ~34 KB -> 4 blocks/CU)

    int t = threadIdx.x;
    int batch = blockIdx.x / BPB;
    int blk   = blockIdx.x % BPB;
    int ev0   = blk * EVPB;
    int cnt   = NEV - ev0; if (cnt > EVPB) cnt = EVPB;
    const f4* bevv = (const f4*)(ev + (size_t)batch * NEV + ev0);

    if (t < NBANDS) hist[t] = 0u;
    __syncthreads();

    // pass 1: ONE global read (nt, batched x4 for MLP), pack to registers
    unsigned int pkd[EPT];   // bd<<22 | y<<12 | x<<1 | p ; 0xFFFFFFFF = tail
    if (cnt == EVPB) {
#pragma unroll
        for (int h = 0; h < EPT / 4; ++h) {
            f4 vv[4];
#pragma unroll
            for (int k = 0; k < 4; ++k)
                vv[k] = __builtin_nontemporal_load(&bevv[t + (h * 4 + k) * THREADS]);
#pragma unroll
            for (int k = 0; k < 4; ++k) {
                unsigned int yi = (unsigned int)(int)vv[k].z;
                unsigned int xi = (unsigned int)(int)vv[k].y;
                unsigned int pb = (vv[k].w == 1.0f) ? 1u : 0u;
                unsigned int bd = yi / 3u;
                pkd[h * 4 + k] = (bd << 22) | (yi << 12) | (xi << 1) | pb;
                atomicAdd(&hist[bd], 1u);
            }
        }
    } else {
#pragma unroll
        for (int k = 0; k < EPT; ++k) {
            int e = t + k * THREADS;
            unsigned int c = 0xFFFFFFFFu;
            if (e < cnt) {
                f4 v = __builtin_nontemporal_load(&bevv[e]);
                unsigned int yi = (unsigned int)(int)v.z;
                unsigned int xi = (unsigned int)(int)v.y;
                unsigned int pb = (v.w == 1.0f) ? 1u : 0u;
                unsigned int bd = yi / 3u;
                c = (bd << 22) | (yi << 12) | (xi << 1) | pb;
                atomicAdd(&hist[bd], 1u);
            }
            pkd[k] = c;
        }
    }
    __syncthreads();

    // exclusive prefix over 240 bands: wave 0 only, threads 0..59 own 4 bands
    if (t < 60) {
        int b4 = t * 4;
        unsigned int own = hist[b4] + hist[b4 + 1] + hist[b4 + 2] + hist[b4 + 3];
        unsigned int incl = own;
        for (int d = 1; d < 64; d <<= 1) {
            unsigned int n = __shfl_up(incl, d);
            if (t >= d) incl += n;
        }
        unsigned int run = incl - own;
        offs[b4] = run;          run += hist[b4];
        offs[b4 + 1] = run;      run += hist[b4 + 1];
        offs[b4 + 2] = run;      run += hist[b4 + 2];
        offs[b4 + 3] = run;
    }
    __syncthreads();

    // publish band-major prefix BEFORE pass 2 mutates offs:
    // pref[(r*BATCH + batch)*BPB + blk]; row NBANDS = total (=cnt)
    {
        unsigned int* pp = pref_g + (size_t)batch * BPB + blk;
        for (int r = t; r < PH; r += THREADS)
            pp[(size_t)r * (BATCH * BPB)] = (r < NBANDS) ? offs[r] : (unsigned int)cnt;
    }
    __syncthreads();

    // pass 2: from REGISTERS, rank, place band-sorted into stage
    if (cnt == EVPB) {
#pragma unroll
        for (int k = 0; k < EPT; ++k) {
            unsigned int c   = pkd[k];
            unsigned int bd  = c >> 22;
            unsigned int yi  = (c >> 12) & 0x3FFu;
            unsigned int xi  = (c >> 1) & 0x7FFu;
            unsigned int pos = (yi - bd * 3u) * 1280u + xi;
            unsigned int e   = (unsigned int)(t + k * THREADS);
            unsigned int pk  = (pos << 20)
                             | (((unsigned int)ev0 + e + 1u) << 1) | (c & 1u);
            unsigned int slot = atomicAdd(&offs[bd], 1u);
            stage[slot] = pk;
        }
    } else {
#pragma unroll
        for (int k = 0; k < EPT; ++k) {
            unsigned int c = pkd[k];
            if (c != 0xFFFFFFFFu) {
                unsigned int bd  = c >> 22;
                unsigned int yi  = (c >> 12) & 0x3FFu;
                unsigned int xi  = (c >> 1) & 0x7FFu;
                unsigned int pos = (yi - bd * 3u) * 1280u + xi;
                unsigned int e   = (unsigned int)(t + k * THREADS);
                unsigned int pk  = (pos << 20)
                                 | (((unsigned int)ev0 + e + 1u) << 1) | (c & 1u);
                unsigned int slot = atomicAdd(&offs[bd], 1u);
                stage[slot] = pk;
            }
        }
    }
    __syncthreads();

    // write the sorted chunk, fully coalesced (keep in L2/L3 for render)
    uint4* dst = (uint4*)(bins + (size_t)blockIdx.x * EVPB);
    const uint4* src = (const uint4*)stage;
    for (int k = t; k < EVPB / 4; k += THREADS)
        dst[k] = src[k];
}

__global__ __launch_bounds__(RTHREADS) void render_k(const unsigned int* __restrict__ pref_g,
                                                     const unsigned int* __restrict__ bins,
                                                     float4* __restrict__ out) {
    __shared__ unsigned int win[BPX];        // 3840 px, 15 KB
    __shared__ unsigned int segbase[BPB];
    __shared__ unsigned int segpref[65];

    int t = threadIdx.x;
    int bandid = blockIdx.x;                 // batch*240 + band
    int batch = bandid / NBANDS;
    int band  = bandid - batch * NBANDS;

    // issue the two coalesced pref rows first; zero win while they fly
    unsigned int p0 = 0u, p1 = 0u;
    if (t < BPB) {
        const unsigned int* r0 = pref_g + ((size_t)band * BATCH + batch) * BPB;
        const unsigned int* r1 = pref_g + ((size_t)(band + 1) * BATCH + batch) * BPB;
        p0 = r0[t];
        p1 = r1[t];
    }
    for (int x = t; x < BPX; x += RTHREADS) win[x] = 0u;

    unsigned int mycnt = 0u;
    if (t < BPB) {
        segbase[t] = (unsigned int)((batch * BPB + t) * EVPB) + p0;
        mycnt = p1 - p0;
    }
    if (t < 64) {                            // wave-0 inclusive scan of 62 counts
        unsigned int v = mycnt;
        for (int d = 1; d < 64; d <<= 1) {
            unsigned int n = __shfl_up(v, d);
            if (t >= d) v += n;
        }
        if (t == 0) segpref[0] = 0u;
        segpref[t + 1] = v;
    }
    __syncthreads();

    unsigned int total = segpref[BPB];       // ~2083
    for (unsigned int j = t; j < total; j += RTHREADS) {
        int lo = 0, hi = BPB - 1;            // largest s with segpref[s] <= j
        while (lo < hi) {
            int mid = (lo + hi + 1) >> 1;
            if (segpref[mid] <= j) lo = mid; else hi = mid - 1;
        }
        unsigned int pk = bins[segbase[lo] + (j - segpref[lo])];
        atomicMax(&win[pk >> 20], pk & 0xFFFFFu);   // LDS atomic
    }
    __syncthreads();

    // write three image rows: 3840 px * 3 ch = 2880 float4; one float4 per
    // thread per iteration; PLAIN stores (write-back via L2 -- R18 variable)
    float4* orow = (float4*)out + (size_t)bandid * (BPX * 3 / 4);
    for (int j = t; j < BPX * 3 / 4; j += RTHREADS) {
        float vals[4];
#pragma unroll
        for (int c = 0; c < 4; ++c) {
            int fi = j * 4 + c;
            int px = fi / 3;
            int ch = fi - px * 3;
            unsigned int k = win[px];
            float val;
            if (k == 0u) val = (ch == 2) ? 510.0f : 255.0f;
            else if (ch == 2) val = 255.0f;
            else if (ch == 0) val = (k & 1u) ? 0.0f : 255.0f;
            else              val = (k & 1u) ? 255.0f : 0.0f;
            vals[c] = val;
        }
        orow[j] = make_float4(vals[0], vals[1], vals[2], vals[3]);
    }
}

extern "C" void kernel_launch(void* const* d_in, const int* in_sizes, int n_in,
                              void* d_out, int out_size, void* d_ws, size_t ws_size,
                              hipStream_t stream) {
    const float4* ev = (const float4*)d_in[0];
    unsigned int* pref_g = (unsigned int*)d_ws;
    unsigned int* bins   = (unsigned int*)((char*)d_ws + 0x400000);
    float4* out = (float4*)d_out;

    scatter_k<<<NBLK, THREADS, 0, stream>>>(ev, pref_g, bins);
    render_k<<<BATCH * NBANDS, RTHREADS, 0, stream>>>(pref_g, bins, out);
}